// Round 1
// baseline (343.097 us; speedup 1.0000x reference)
//
#include <hip/hip_runtime.h>
#include <hip/hip_bf16.h>

// Problem constants
#define BATCH 256
#define DIM   2048
#define NMEM  16384   // C_CAM * P
#define PCLS  2048
#define CCAM  8
#define KSEL  50
#define T_INV 14.285714285714285714f   // 1 / 0.07

typedef __bf16 bf16x8 __attribute__((ext_vector_type(8)));
typedef float  f32x4  __attribute__((ext_vector_type(4)));

static __device__ __forceinline__ unsigned int f2bf(float f) {
  unsigned int u = __float_as_uint(f);
  return (u + 0x7FFFu + ((u >> 16) & 1u)) >> 16;   // RNE truncate to bf16
}
static __device__ __forceinline__ unsigned int pk2(float lo, float hi) {
  return f2bf(lo) | (f2bf(hi) << 16);
}

// ---------------------------------------------------------------------------
// Kernel 1: row-normalize inputs, cast to bf16.  grid=256 blocks x 256 thr
// ---------------------------------------------------------------------------
__global__ __launch_bounds__(256) void norm_cast_kernel(
    const float* __restrict__ in, unsigned short* __restrict__ xb) {
  __shared__ float red[256];
  const int b = blockIdx.x, t = threadIdx.x;
  const float4* row = (const float4*)(in + (size_t)b * DIM);
  float4 a0 = row[t];
  float4 a1 = row[t + 256];
  float ss = a0.x*a0.x + a0.y*a0.y + a0.z*a0.z + a0.w*a0.w
           + a1.x*a1.x + a1.y*a1.y + a1.z*a1.z + a1.w*a1.w;
  red[t] = ss; __syncthreads();
  for (int s = 128; s > 0; s >>= 1) { if (t < s) red[t] += red[t + s]; __syncthreads(); }
  const float rn = rsqrtf(red[0]);
  ushort4 o0, o1;
  o0.x = (unsigned short)f2bf(a0.x*rn); o0.y = (unsigned short)f2bf(a0.y*rn);
  o0.z = (unsigned short)f2bf(a0.z*rn); o0.w = (unsigned short)f2bf(a0.w*rn);
  o1.x = (unsigned short)f2bf(a1.x*rn); o1.y = (unsigned short)f2bf(a1.y*rn);
  o1.z = (unsigned short)f2bf(a1.z*rn); o1.w = (unsigned short)f2bf(a1.w*rn);
  *(ushort4*)&xb[(size_t)b * DIM + t * 4]         = o0;
  *(ushort4*)&xb[(size_t)b * DIM + (t + 256) * 4] = o1;
}

// ---------------------------------------------------------------------------
// Kernel 2: logits = x(bf16) @ tempV^T  (tempV fp32 converted in staging)
// 128x128 tile, BK=32, 4 waves of 4x4 16x16x32 MFMA frags (m93 pattern,
// register-prefetch software pipeline). grid = (128 Ntiles, 2 Mtiles)
// ---------------------------------------------------------------------------
#define BM 128
#define BN 128
#define BK 32
#define LDT 40   // padded LDS row stride (bf16 elems): 32 + 8

__global__ __launch_bounds__(256) void gemm_kernel(
    const unsigned short* __restrict__ X,   // [256][2048] bf16
    const float* __restrict__ V,            // [16384][2048] fp32
    float* __restrict__ C) {                // [256][16384] fp32
  __shared__ unsigned short As[BM * LDT];
  __shared__ unsigned short Bs[BN * LDT];
  const int t  = threadIdx.x;
  const int n0 = blockIdx.x * BN;
  const int m0 = blockIdx.y * BM;
  const int lane = t & 63;
  const int w    = t >> 6;
  const int wm   = (w >> 1) * 64;
  const int wn   = (w & 1) * 64;

  f32x4 acc[4][4];
#pragma unroll
  for (int i = 0; i < 4; i++)
#pragma unroll
    for (int j = 0; j < 4; j++) acc[i][j] = (f32x4){0.f, 0.f, 0.f, 0.f};

  // staging: thread -> (row sr, 16-elem half sh)
  const int sr = t >> 1;
  const int sh = (t & 1) * 16;
  const unsigned short* Xp = X + (size_t)(m0 + sr) * DIM + sh;
  const float*          Vp = V + (size_t)(n0 + sr) * DIM + sh;

  // prefetch k=0
  uint4  a0 = *(const uint4*)Xp;
  uint4  a1 = *(const uint4*)(Xp + 8);
  float4 b0 = *(const float4*)Vp;
  float4 b1 = *(const float4*)(Vp + 4);
  float4 b2 = *(const float4*)(Vp + 8);
  float4 b3 = *(const float4*)(Vp + 12);

  const int fr = lane & 15;
  const int fk = (lane >> 4) * 8;

  for (int k0 = 0; k0 < DIM; k0 += BK) {
    __syncthreads();   // previous iteration's frag reads done
    *(uint4*)&As[sr * LDT + sh]     = a0;
    *(uint4*)&As[sr * LDT + sh + 8] = a1;
    uint4 p0, p1;
    p0.x = pk2(b0.x, b0.y); p0.y = pk2(b0.z, b0.w);
    p0.z = pk2(b1.x, b1.y); p0.w = pk2(b1.z, b1.w);
    p1.x = pk2(b2.x, b2.y); p1.y = pk2(b2.z, b2.w);
    p1.z = pk2(b3.x, b3.y); p1.w = pk2(b3.z, b3.w);
    *(uint4*)&Bs[sr * LDT + sh]     = p0;
    *(uint4*)&Bs[sr * LDT + sh + 8] = p1;
    __syncthreads();

    if (k0 + BK < DIM) {  // issue next-tile global loads; consumed next iter
      a0 = *(const uint4*)(Xp + k0 + BK);
      a1 = *(const uint4*)(Xp + k0 + BK + 8);
      b0 = *(const float4*)(Vp + k0 + BK);
      b1 = *(const float4*)(Vp + k0 + BK + 4);
      b2 = *(const float4*)(Vp + k0 + BK + 8);
      b3 = *(const float4*)(Vp + k0 + BK + 12);
    }

    bf16x8 aF[4], bF[4];
#pragma unroll
    for (int i = 0; i < 4; i++)
      aF[i] = *(const bf16x8*)&As[(wm + i * 16 + fr) * LDT + fk];
#pragma unroll
    for (int j = 0; j < 4; j++)
      bF[j] = *(const bf16x8*)&Bs[(wn + j * 16 + fr) * LDT + fk];
#pragma unroll
    for (int i = 0; i < 4; i++)
#pragma unroll
      for (int j = 0; j < 4; j++)
        acc[i][j] = __builtin_amdgcn_mfma_f32_16x16x32_bf16(aF[i], bF[j], acc[i][j], 0, 0, 0);
  }

  // epilogue: C/D layout col=lane&15, row=(lane>>4)*4+reg  [m89/m91 verified]
  const int cr = (lane >> 4) * 4;
  const int cc = lane & 15;
#pragma unroll
  for (int i = 0; i < 4; i++)
#pragma unroll
    for (int j = 0; j < 4; j++)
#pragma unroll
      for (int r = 0; r < 4; r++)
        C[(size_t)(m0 + wm + i * 16 + cr + r) * NMEM + (n0 + wn + j * 16 + cc)] =
            acc[i][j][r];
}

// ---------------------------------------------------------------------------
// Kernel 3: per-row losses. One block (256 thr) per sample.
//  - intra CE over own camera bank (before masking)
//  - mask 8 positives, top-50 via 256 per-thread local maxima + 50 wave-wide
//    argmax extractions (only wave 0 runs the loop)
//  - inter logsumexp over {8 ori, 50 sel}
// ---------------------------------------------------------------------------
__global__ __launch_bounds__(256) void row_loss_kernel(
    const float* __restrict__ logits,
    const int* __restrict__ labels, const int* __restrict__ cams,
    float* __restrict__ ce_out, float* __restrict__ lossk_out) {
  __shared__ float vals[NMEM];
  __shared__ float red[256];
  __shared__ float candv[256];
  __shared__ int   candi[256];
  __shared__ float selv[64];

  const int b = blockIdx.x, t = threadIdx.x;
  const float4* src = (const float4*)(logits + (size_t)b * NMEM);
#pragma unroll
  for (int i = 0; i < 16; i++) ((float4*)vals)[t + 256 * i] = src[t + 256 * i];
  const int cam = cams[b], label = labels[b];
  __syncthreads();

  // ---- intra CE over [cam*PCLS, +PCLS) ----
  const int s0 = cam * PCLS;
  float m = -1e30f;
#pragma unroll
  for (int i = 0; i < 8; i++) m = fmaxf(m, vals[s0 + t + 256 * i]);
  red[t] = m; __syncthreads();
  for (int s = 128; s > 0; s >>= 1) { if (t < s) red[t] = fmaxf(red[t], red[t + s]); __syncthreads(); }
  m = red[0]; __syncthreads();
  float S = 0.f;
#pragma unroll
  for (int i = 0; i < 8; i++) S += __expf((vals[s0 + t + 256 * i] - m) * T_INV);
  red[t] = S; __syncthreads();
  for (int s = 128; s > 0; s >>= 1) { if (t < s) red[t] += red[t + s]; __syncthreads(); }
  if (t == 0) {
    float lse = m * T_INV + logf(red[0]);
    ce_out[b] = lse - vals[s0 + label] * T_INV;
  }

  // ---- ori values (pre-mask), then mask positives ----
  float ov[CCAM];
#pragma unroll
  for (int c = 0; c < CCAM; c++) ov[c] = vals[c * PCLS + label];
  __syncthreads();                 // everyone read ov before masking
  if (t < CCAM) vals[t * PCLS + label] = -1e30f;
  __syncthreads();

  // ---- per-thread local max over strided segment {t + 256*i} ----
  float cm = -1e30f; int ci = t;
#pragma unroll
  for (int i = 0; i < 64; i++) {
    float x = vals[t + 256 * i];
    if (x > cm) { cm = x; ci = t + 256 * i; }
  }
  candv[t] = cm; candi[t] = ci;
  __syncthreads();

  if (t < 64) {
    const int l = t;
    for (int it = 0; it < KSEL; it++) {
      // argmax over 256 candidates
      float v = -2e30f; int slot = 0;
#pragma unroll
      for (int j = 0; j < 4; j++) {
        float c = candv[l + 64 * j];
        if (c > v) { v = c; slot = l + 64 * j; }
      }
#pragma unroll
      for (int off = 32; off > 0; off >>= 1) {
        float vv = __shfl_xor(v, off);
        int   ss2 = __shfl_xor(slot, off);
        if (vv > v || (vv == v && ss2 < slot)) { v = vv; slot = ss2; }
      }
      const int gidx = candi[slot];
      if (l == 0) { selv[it] = v; vals[gidx] = -1e30f; }
      // recompute candidate for `slot` (its elements are slot + 256*l)
      float x = vals[slot + 256 * l];
      int  xi = slot + 256 * l;
#pragma unroll
      for (int off = 32; off > 0; off >>= 1) {
        float vv = __shfl_xor(x, off);
        int   ii = __shfl_xor(xi, off);
        if (vv > x || (vv == x && ii < xi)) { x = vv; xi = ii; }
      }
      if (l == 0) { candv[slot] = x; candi[slot] = xi; }
    }
  }
  __syncthreads();

  if (t == 0) {
    float mo = -1e30f;
#pragma unroll
    for (int c = 0; c < CCAM; c++) mo = fmaxf(mo, ov[c]);
    float mcat = fmaxf(mo, selv[0]);   // selv[0] = largest selected
    float S2 = 0.f, sumo = 0.f;
#pragma unroll
    for (int c = 0; c < CCAM; c++) { S2 += __expf((ov[c] - mcat) * T_INV); sumo += ov[c]; }
    for (int i = 0; i < KSEL; i++) S2 += __expf((selv[i] - mcat) * T_INV);
    float lse_c = mcat * T_INV + logf(S2);
    lossk_out[b] = lse_c - (sumo * T_INV) * (1.0f / CCAM);
  }
}

// ---------------------------------------------------------------------------
// Kernel 4: deterministic per-camera segment means -> 2 scalars
// ---------------------------------------------------------------------------
__global__ __launch_bounds__(64) void finalize_kernel(
    const float* __restrict__ ce, const float* __restrict__ lossk,
    const int* __restrict__ cams, float* __restrict__ out) {
  __shared__ float si[CCAM], sk[CCAM], cnt[CCAM];
  const int t = threadIdx.x;
  if (t < CCAM) {
    float a = 0.f, b = 0.f; int n = 0;
    for (int i = 0; i < BATCH; i++) {
      if (cams[i] == t) { a += ce[i]; b += lossk[i]; n++; }
    }
    si[t] = a; sk[t] = b; cnt[t] = (float)n;
  }
  __syncthreads();
  if (t == 0) {
    float li = 0.f, lk = 0.f;
    for (int c = 0; c < CCAM; c++) {
      if (cnt[c] > 0.f) { li += si[c] / cnt[c]; lk += sk[c] / cnt[c]; }
    }
    out[0] = li;
    out[1] = 0.5f * lk;
  }
}

// ---------------------------------------------------------------------------
extern "C" void kernel_launch(void* const* d_in, const int* in_sizes, int n_in,
                              void* d_out, int out_size, void* d_ws, size_t ws_size,
                              hipStream_t stream) {
  const float* inputs = (const float*)d_in[0];   // [256][2048]
  const int*   labels = (const int*)d_in[1];     // [256]
  const int*   cams   = (const int*)d_in[2];     // [256]
  const float* tempV  = (const float*)d_in[3];   // [16384][2048]
  float* out = (float*)d_out;

  char* ws = (char*)d_ws;
  unsigned short* xb  = (unsigned short*)ws;                       // 1 MB
  float* logits       = (float*)(ws + (1u << 20));                 // 16 MB
  float* ce           = (float*)(ws + (1u << 20) + (16u << 20));   // 1 KB
  float* lossk        = (float*)(ws + (1u << 20) + (16u << 20) + 1024);

  norm_cast_kernel<<<BATCH, 256, 0, stream>>>(inputs, xb);
  gemm_kernel<<<dim3(NMEM / BN, BATCH / BM), 256, 0, stream>>>(xb, tempV, logits);
  row_loss_kernel<<<BATCH, 256, 0, stream>>>(logits, labels, cams, ce, lossk);
  finalize_kernel<<<1, 64, 0, stream>>>(ce, lossk, cams, out);
}

// Round 2
// 341.520 us; speedup vs baseline: 1.0046x; 1.0046x over previous
//
#include <hip/hip_runtime.h>
#include <hip/hip_bf16.h>

// Problem constants
#define BATCH 256
#define DIM   2048
#define NMEM  16384   // C_CAM * P
#define PCLS  2048
#define CCAM  8
#define KSEL  50
#define T_INV 14.285714285714285714f   // 1 / 0.07

typedef __bf16 bf16x8 __attribute__((ext_vector_type(8)));
typedef float  f32x4  __attribute__((ext_vector_type(4)));

static __device__ __forceinline__ unsigned int f2bf(float f) {
  unsigned int u = __float_as_uint(f);
  return (u + 0x7FFFu + ((u >> 16) & 1u)) >> 16;   // RNE truncate to bf16
}
static __device__ __forceinline__ unsigned int pk2(float lo, float hi) {
  return f2bf(lo) | (f2bf(hi) << 16);
}

// ---------------------------------------------------------------------------
// Kernel 1: row-normalize inputs, cast to bf16.  grid=256 blocks x 256 thr
// ---------------------------------------------------------------------------
__global__ __launch_bounds__(256) void norm_cast_kernel(
    const float* __restrict__ in, unsigned short* __restrict__ xb) {
  __shared__ float red[256];
  const int b = blockIdx.x, t = threadIdx.x;
  const float4* row = (const float4*)(in + (size_t)b * DIM);
  float4 a0 = row[t];
  float4 a1 = row[t + 256];
  float ss = a0.x*a0.x + a0.y*a0.y + a0.z*a0.z + a0.w*a0.w
           + a1.x*a1.x + a1.y*a1.y + a1.z*a1.z + a1.w*a1.w;
  red[t] = ss; __syncthreads();
  for (int s = 128; s > 0; s >>= 1) { if (t < s) red[t] += red[t + s]; __syncthreads(); }
  const float rn = rsqrtf(red[0]);
  ushort4 o0, o1;
  o0.x = (unsigned short)f2bf(a0.x*rn); o0.y = (unsigned short)f2bf(a0.y*rn);
  o0.z = (unsigned short)f2bf(a0.z*rn); o0.w = (unsigned short)f2bf(a0.w*rn);
  o1.x = (unsigned short)f2bf(a1.x*rn); o1.y = (unsigned short)f2bf(a1.y*rn);
  o1.z = (unsigned short)f2bf(a1.z*rn); o1.w = (unsigned short)f2bf(a1.w*rn);
  *(ushort4*)&xb[(size_t)b * DIM + t * 4]         = o0;
  *(ushort4*)&xb[(size_t)b * DIM + (t + 256) * 4] = o1;
}

// ---------------------------------------------------------------------------
// Kernel 2: logits = x(bf16) @ tempV^T  (tempV fp32, converted in staging)
// BM=256 (full batch, V read exactly once), BN=64, BK=32.
// 512 threads = 8 waves in 4(M) x 2(N) grid; wave tile 64x32 (4x2 frags).
// grid = 256 N-tiles  ->  1 block/CU, 8 waves/CU.
// ---------------------------------------------------------------------------
#define BM 256
#define BN 64
#define BK 32
#define LDT 40   // padded LDS row stride (bf16 elems): 32 + 8

__global__ __launch_bounds__(512, 2) void gemm_kernel(
    const unsigned short* __restrict__ X,   // [256][2048] bf16
    const float* __restrict__ V,            // [16384][2048] fp32
    float* __restrict__ C) {                // [256][16384] fp32
  __shared__ unsigned short As[BM * LDT];   // 20 KB
  __shared__ unsigned short Bs[BN * LDT];   // 5 KB
  const int t  = threadIdx.x;
  const int n0 = blockIdx.x * BN;
  const int lane = t & 63;
  const int w    = t >> 6;
  const int wm   = (w >> 1) * 64;   // 0,64,128,192
  const int wn   = (w & 1) * 32;    // 0,32

  f32x4 acc[4][2];
#pragma unroll
  for (int i = 0; i < 4; i++)
#pragma unroll
    for (int j = 0; j < 2; j++) acc[i][j] = (f32x4){0.f, 0.f, 0.f, 0.f};

  // staging: A -> thread covers 16 bf16 of one row; B -> one float4 of one row
  const int sr = t >> 1;            // 0..255
  const int sh = (t & 1) * 16;
  const int rb = t >> 3;            // 0..63
  const int cb = (t & 7) * 4;
  const unsigned short* Xp = X + (size_t)sr * DIM + sh;
  const float*          Vp = V + (size_t)(n0 + rb) * DIM + cb;

  // prefetch k=0
  uint4  a0 = *(const uint4*)Xp;
  uint4  a1 = *(const uint4*)(Xp + 8);
  float4 b0 = *(const float4*)Vp;

  const int fr = lane & 15;
  const int fk = (lane >> 4) * 8;

  for (int k0 = 0; k0 < DIM; k0 += BK) {
    __syncthreads();   // previous iteration's frag reads done
    *(uint4*)&As[sr * LDT + sh]     = a0;
    *(uint4*)&As[sr * LDT + sh + 8] = a1;
    uint2 p;
    p.x = pk2(b0.x, b0.y);
    p.y = pk2(b0.z, b0.w);
    *(uint2*)&Bs[rb * LDT + cb] = p;
    __syncthreads();

    if (k0 + BK < DIM) {  // issue next-tile global loads; consumed next iter
      a0 = *(const uint4*)(Xp + k0 + BK);
      a1 = *(const uint4*)(Xp + k0 + BK + 8);
      b0 = *(const float4*)(Vp + k0 + BK);
    }

    bf16x8 aF[4], bF[2];
#pragma unroll
    for (int i = 0; i < 4; i++)
      aF[i] = *(const bf16x8*)&As[(wm + i * 16 + fr) * LDT + fk];
#pragma unroll
    for (int j = 0; j < 2; j++)
      bF[j] = *(const bf16x8*)&Bs[(wn + j * 16 + fr) * LDT + fk];
#pragma unroll
    for (int i = 0; i < 4; i++)
#pragma unroll
      for (int j = 0; j < 2; j++)
        acc[i][j] = __builtin_amdgcn_mfma_f32_16x16x32_bf16(aF[i], bF[j], acc[i][j], 0, 0, 0);
  }

  // epilogue: C/D layout col=lane&15, row=(lane>>4)*4+reg  [m89/m91 verified]
  const int cr = (lane >> 4) * 4;
  const int cc = lane & 15;
#pragma unroll
  for (int i = 0; i < 4; i++)
#pragma unroll
    for (int j = 0; j < 2; j++)
#pragma unroll
      for (int r = 0; r < 4; r++)
        C[(size_t)(wm + i * 16 + cr + r) * NMEM + (n0 + wn + j * 16 + cc)] =
            acc[i][j][r];
}

// ---------------------------------------------------------------------------
// Kernel 3: per-row losses. One block (256 thr) per sample.
//  - intra CE over own camera bank (before masking)
//  - mask 8 positives, top-50 via 256 per-thread local maxima + 50 wave-wide
//    argmax extractions (only wave 0 runs the loop)
//  - inter logsumexp over {8 ori, 50 sel}
// ---------------------------------------------------------------------------
__global__ __launch_bounds__(256) void row_loss_kernel(
    const float* __restrict__ logits,
    const int* __restrict__ labels, const int* __restrict__ cams,
    float* __restrict__ ce_out, float* __restrict__ lossk_out) {
  __shared__ float vals[NMEM];
  __shared__ float red[256];
  __shared__ float candv[256];
  __shared__ int   candi[256];
  __shared__ float selv[64];

  const int b = blockIdx.x, t = threadIdx.x;
  const float4* src = (const float4*)(logits + (size_t)b * NMEM);
#pragma unroll
  for (int i = 0; i < 16; i++) ((float4*)vals)[t + 256 * i] = src[t + 256 * i];
  const int cam = cams[b], label = labels[b];
  __syncthreads();

  // ---- intra CE over [cam*PCLS, +PCLS) ----
  const int s0 = cam * PCLS;
  float m = -1e30f;
#pragma unroll
  for (int i = 0; i < 8; i++) m = fmaxf(m, vals[s0 + t + 256 * i]);
  red[t] = m; __syncthreads();
  for (int s = 128; s > 0; s >>= 1) { if (t < s) red[t] = fmaxf(red[t], red[t + s]); __syncthreads(); }
  m = red[0]; __syncthreads();
  float S = 0.f;
#pragma unroll
  for (int i = 0; i < 8; i++) S += __expf((vals[s0 + t + 256 * i] - m) * T_INV);
  red[t] = S; __syncthreads();
  for (int s = 128; s > 0; s >>= 1) { if (t < s) red[t] += red[t + s]; __syncthreads(); }
  if (t == 0) {
    float lse = m * T_INV + logf(red[0]);
    ce_out[b] = lse - vals[s0 + label] * T_INV;
  }

  // ---- ori values (pre-mask), then mask positives ----
  float ov[CCAM];
#pragma unroll
  for (int c = 0; c < CCAM; c++) ov[c] = vals[c * PCLS + label];
  __syncthreads();                 // everyone read ov before masking
  if (t < CCAM) vals[t * PCLS + label] = -1e30f;
  __syncthreads();

  // ---- per-thread local max over strided segment {t + 256*i} ----
  float cm = -1e30f; int ci = t;
#pragma unroll
  for (int i = 0; i < 64; i++) {
    float x = vals[t + 256 * i];
    if (x > cm) { cm = x; ci = t + 256 * i; }
  }
  candv[t] = cm; candi[t] = ci;
  __syncthreads();

  if (t < 64) {
    const int l = t;
    for (int it = 0; it < KSEL; it++) {
      // argmax over 256 candidates
      float v = -2e30f; int slot = 0;
#pragma unroll
      for (int j = 0; j < 4; j++) {
        float c = candv[l + 64 * j];
        if (c > v) { v = c; slot = l + 64 * j; }
      }
#pragma unroll
      for (int off = 32; off > 0; off >>= 1) {
        float vv = __shfl_xor(v, off);
        int   ss2 = __shfl_xor(slot, off);
        if (vv > v || (vv == v && ss2 < slot)) { v = vv; slot = ss2; }
      }
      const int gidx = candi[slot];
      if (l == 0) { selv[it] = v; vals[gidx] = -1e30f; }
      // recompute candidate for `slot` (its elements are slot + 256*l)
      float x = vals[slot + 256 * l];
      int  xi = slot + 256 * l;
#pragma unroll
      for (int off = 32; off > 0; off >>= 1) {
        float vv = __shfl_xor(x, off);
        int   ii = __shfl_xor(xi, off);
        if (vv > x || (vv == x && ii < xi)) { x = vv; xi = ii; }
      }
      if (l == 0) { candv[slot] = x; candi[slot] = xi; }
    }
  }
  __syncthreads();

  if (t == 0) {
    float mo = -1e30f;
#pragma unroll
    for (int c = 0; c < CCAM; c++) mo = fmaxf(mo, ov[c]);
    float mcat = fmaxf(mo, selv[0]);   // selv[0] = largest selected
    float S2 = 0.f, sumo = 0.f;
#pragma unroll
    for (int c = 0; c < CCAM; c++) { S2 += __expf((ov[c] - mcat) * T_INV); sumo += ov[c]; }
    for (int i = 0; i < KSEL; i++) S2 += __expf((selv[i] - mcat) * T_INV);
    float lse_c = mcat * T_INV + logf(S2);
    lossk_out[b] = lse_c - (sumo * T_INV) * (1.0f / CCAM);
  }
}

// ---------------------------------------------------------------------------
// Kernel 4: deterministic per-camera segment means -> 2 scalars.
// Stage the 256 rows in LDS first (parallel coalesced loads), then 8 threads
// scan LDS (fast) instead of chasing global latency.
// ---------------------------------------------------------------------------
__global__ __launch_bounds__(256) void finalize_kernel(
    const float* __restrict__ ce, const float* __restrict__ lossk,
    const int* __restrict__ cams, float* __restrict__ out) {
  __shared__ float ce_s[BATCH], lk_s[BATCH];
  __shared__ int   cam_s[BATCH];
  __shared__ float si[CCAM], sk[CCAM], cnt[CCAM];
  const int t = threadIdx.x;
  ce_s[t]  = ce[t];
  lk_s[t]  = lossk[t];
  cam_s[t] = cams[t];
  __syncthreads();
  if (t < CCAM) {
    float a = 0.f, b = 0.f; int n = 0;
    for (int i = 0; i < BATCH; i++) {
      if (cam_s[i] == t) { a += ce_s[i]; b += lk_s[i]; n++; }
    }
    si[t] = a; sk[t] = b; cnt[t] = (float)n;
  }
  __syncthreads();
  if (t == 0) {
    float li = 0.f, lk = 0.f;
    for (int c = 0; c < CCAM; c++) {
      if (cnt[c] > 0.f) { li += si[c] / cnt[c]; lk += sk[c] / cnt[c]; }
    }
    out[0] = li;
    out[1] = 0.5f * lk;
  }
}

// ---------------------------------------------------------------------------
extern "C" void kernel_launch(void* const* d_in, const int* in_sizes, int n_in,
                              void* d_out, int out_size, void* d_ws, size_t ws_size,
                              hipStream_t stream) {
  const float* inputs = (const float*)d_in[0];   // [256][2048]
  const int*   labels = (const int*)d_in[1];     // [256]
  const int*   cams   = (const int*)d_in[2];     // [256]
  const float* tempV  = (const float*)d_in[3];   // [16384][2048]
  float* out = (float*)d_out;

  char* ws = (char*)d_ws;
  unsigned short* xb  = (unsigned short*)ws;                       // 1 MB
  float* logits       = (float*)(ws + (1u << 20));                 // 16 MB
  float* ce           = (float*)(ws + (1u << 20) + (16u << 20));   // 1 KB
  float* lossk        = (float*)(ws + (1u << 20) + (16u << 20) + 1024);

  norm_cast_kernel<<<BATCH, 256, 0, stream>>>(inputs, xb);
  gemm_kernel<<<NMEM / BN, 512, 0, stream>>>(xb, tempV, logits);
  row_loss_kernel<<<BATCH, 256, 0, stream>>>(logits, labels, cams, ce, lossk);
  finalize_kernel<<<1, 256, 0, stream>>>(ce, lossk, cams, out);
}

// Round 3
// 329.416 us; speedup vs baseline: 1.0415x; 1.0367x over previous
//
#include <hip/hip_runtime.h>
#include <hip/hip_bf16.h>

// Problem constants
#define BATCH 256
#define DIM   2048
#define NMEM  16384   // C_CAM * P
#define PCLS  2048
#define CCAM  8
#define KSEL  50
#define T_INV 14.285714285714285714f   // 1 / 0.07

typedef __bf16 bf16x8 __attribute__((ext_vector_type(8)));
typedef float  f32x4  __attribute__((ext_vector_type(4)));

static __device__ __forceinline__ unsigned int f2bf(float f) {
  unsigned int u = __float_as_uint(f);
  return (u + 0x7FFFu + ((u >> 16) & 1u)) >> 16;   // RNE truncate to bf16
}
static __device__ __forceinline__ unsigned int pk2(float lo, float hi) {
  return f2bf(lo) | (f2bf(hi) << 16);
}

// ---------------------------------------------------------------------------
// Kernel 1: row-normalize inputs, cast to bf16.  grid=256 blocks x 256 thr
// ---------------------------------------------------------------------------
__global__ __launch_bounds__(256) void norm_cast_kernel(
    const float* __restrict__ in, unsigned short* __restrict__ xb) {
  __shared__ float red[256];
  const int b = blockIdx.x, t = threadIdx.x;
  const float4* row = (const float4*)(in + (size_t)b * DIM);
  float4 a0 = row[t];
  float4 a1 = row[t + 256];
  float ss = a0.x*a0.x + a0.y*a0.y + a0.z*a0.z + a0.w*a0.w
           + a1.x*a1.x + a1.y*a1.y + a1.z*a1.z + a1.w*a1.w;
  red[t] = ss; __syncthreads();
  for (int s = 128; s > 0; s >>= 1) { if (t < s) red[t] += red[t + s]; __syncthreads(); }
  const float rn = rsqrtf(red[0]);
  ushort4 o0, o1;
  o0.x = (unsigned short)f2bf(a0.x*rn); o0.y = (unsigned short)f2bf(a0.y*rn);
  o0.z = (unsigned short)f2bf(a0.z*rn); o0.w = (unsigned short)f2bf(a0.w*rn);
  o1.x = (unsigned short)f2bf(a1.x*rn); o1.y = (unsigned short)f2bf(a1.y*rn);
  o1.z = (unsigned short)f2bf(a1.z*rn); o1.w = (unsigned short)f2bf(a1.w*rn);
  *(ushort4*)&xb[(size_t)b * DIM + t * 4]         = o0;
  *(ushort4*)&xb[(size_t)b * DIM + (t + 256) * 4] = o1;
}

// ---------------------------------------------------------------------------
// Kernel 2: logits = x(bf16) @ tempV^T  (tempV fp32, converted in staging)
// BM=128, BN=64, BK=32. 256 threads = 4 waves in 2(M) x 2(N) grid; wave tile
// 64x32 (4x2 frags). grid = dim3(2 Mtiles, 256 Ntiles) = 512 blocks
// -> 2 independent barrier domains per CU (the latency-hiding lever).
// M is the fast grid dim so both M-halves of an N-tile share V via L2/L3.
// ---------------------------------------------------------------------------
#define BM 128
#define BN 64
#define BK 32
#define LDT 40   // padded LDS row stride (bf16 elems): 32 + 8

__global__ __launch_bounds__(256, 2) void gemm_kernel(
    const unsigned short* __restrict__ X,   // [256][2048] bf16
    const float* __restrict__ V,            // [16384][2048] fp32
    float* __restrict__ C) {                // [256][16384] fp32
  __shared__ unsigned short As[BM * LDT];   // 10 KB
  __shared__ unsigned short Bs[BN * LDT];   // 5 KB
  const int t  = threadIdx.x;
  const int m0 = blockIdx.x * BM;
  const int n0 = blockIdx.y * BN;
  const int lane = t & 63;
  const int w    = t >> 6;
  const int wm   = (w >> 1) * 64;   // 0,64
  const int wn   = (w & 1) * 32;    // 0,32

  f32x4 acc[4][2];
#pragma unroll
  for (int i = 0; i < 4; i++)
#pragma unroll
    for (int j = 0; j < 2; j++) acc[i][j] = (f32x4){0.f, 0.f, 0.f, 0.f};

  // staging: A -> thread covers 16 bf16 of one row (128 rows x 2 halves)
  //          B -> thread covers 8 fp32 of one row   (64 rows x 4 quarters)
  const int sr = t >> 1;            // 0..127
  const int sh = (t & 1) * 16;
  const int rb = t >> 2;            // 0..63
  const int cb = (t & 3) * 8;
  const unsigned short* Xp = X + (size_t)(m0 + sr) * DIM + sh;
  const float*          Vp = V + (size_t)(n0 + rb) * DIM + cb;

  // prefetch k=0
  uint4  a0 = *(const uint4*)Xp;
  uint4  a1 = *(const uint4*)(Xp + 8);
  float4 b0 = *(const float4*)Vp;
  float4 b1 = *(const float4*)(Vp + 4);

  const int fr = lane & 15;
  const int fk = (lane >> 4) * 8;

  for (int k0 = 0; k0 < DIM; k0 += BK) {
    __syncthreads();   // previous iteration's frag reads done
    *(uint4*)&As[sr * LDT + sh]     = a0;
    *(uint4*)&As[sr * LDT + sh + 8] = a1;
    uint4 p;
    p.x = pk2(b0.x, b0.y); p.y = pk2(b0.z, b0.w);
    p.z = pk2(b1.x, b1.y); p.w = pk2(b1.z, b1.w);
    *(uint4*)&Bs[rb * LDT + cb] = p;
    __syncthreads();

    if (k0 + BK < DIM) {  // issue next-tile global loads; consumed next iter
      a0 = *(const uint4*)(Xp + k0 + BK);
      a1 = *(const uint4*)(Xp + k0 + BK + 8);
      b0 = *(const float4*)(Vp + k0 + BK);
      b1 = *(const float4*)(Vp + k0 + BK + 4);
    }

    bf16x8 aF[4], bF[2];
#pragma unroll
    for (int i = 0; i < 4; i++)
      aF[i] = *(const bf16x8*)&As[(wm + i * 16 + fr) * LDT + fk];
#pragma unroll
    for (int j = 0; j < 2; j++)
      bF[j] = *(const bf16x8*)&Bs[(wn + j * 16 + fr) * LDT + fk];
#pragma unroll
    for (int i = 0; i < 4; i++)
#pragma unroll
      for (int j = 0; j < 2; j++)
        acc[i][j] = __builtin_amdgcn_mfma_f32_16x16x32_bf16(aF[i], bF[j], acc[i][j], 0, 0, 0);
  }

  // epilogue: C/D layout col=lane&15, row=(lane>>4)*4+reg  [m89/m91 verified]
  const int cr = (lane >> 4) * 4;
  const int cc = lane & 15;
#pragma unroll
  for (int i = 0; i < 4; i++)
#pragma unroll
    for (int j = 0; j < 2; j++)
#pragma unroll
      for (int r = 0; r < 4; r++)
        C[(size_t)(m0 + wm + i * 16 + cr + r) * NMEM + (n0 + wn + j * 16 + cc)] =
            acc[i][j][r];
}

// ---------------------------------------------------------------------------
// Kernel 3: per-row losses. One block (256 thr) per sample.
//  - intra CE over own camera bank (before masking)
//  - mask 8 positives, top-50 via 256 per-thread local maxima + 50 wave-wide
//    argmax extractions (only wave 0 runs the loop)
//  - inter logsumexp over {8 ori, 50 sel}
// ---------------------------------------------------------------------------
__global__ __launch_bounds__(256) void row_loss_kernel(
    const float* __restrict__ logits,
    const int* __restrict__ labels, const int* __restrict__ cams,
    float* __restrict__ ce_out, float* __restrict__ lossk_out) {
  __shared__ float vals[NMEM];
  __shared__ float red[256];
  __shared__ float candv[256];
  __shared__ int   candi[256];
  __shared__ float selv[64];

  const int b = blockIdx.x, t = threadIdx.x;
  const float4* src = (const float4*)(logits + (size_t)b * NMEM);
#pragma unroll
  for (int i = 0; i < 16; i++) ((float4*)vals)[t + 256 * i] = src[t + 256 * i];
  const int cam = cams[b], label = labels[b];
  __syncthreads();

  // ---- intra CE over [cam*PCLS, +PCLS) ----
  const int s0 = cam * PCLS;
  float m = -1e30f;
#pragma unroll
  for (int i = 0; i < 8; i++) m = fmaxf(m, vals[s0 + t + 256 * i]);
  red[t] = m; __syncthreads();
  for (int s = 128; s > 0; s >>= 1) { if (t < s) red[t] = fmaxf(red[t], red[t + s]); __syncthreads(); }
  m = red[0]; __syncthreads();
  float S = 0.f;
#pragma unroll
  for (int i = 0; i < 8; i++) S += __expf((vals[s0 + t + 256 * i] - m) * T_INV);
  red[t] = S; __syncthreads();
  for (int s = 128; s > 0; s >>= 1) { if (t < s) red[t] += red[t + s]; __syncthreads(); }
  if (t == 0) {
    float lse = m * T_INV + logf(red[0]);
    ce_out[b] = lse - vals[s0 + label] * T_INV;
  }

  // ---- ori values (pre-mask), then mask positives ----
  float ov[CCAM];
#pragma unroll
  for (int c = 0; c < CCAM; c++) ov[c] = vals[c * PCLS + label];
  __syncthreads();                 // everyone read ov before masking
  if (t < CCAM) vals[t * PCLS + label] = -1e30f;
  __syncthreads();

  // ---- per-thread local max over strided segment {t + 256*i} ----
  float cm = -1e30f; int ci = t;
#pragma unroll
  for (int i = 0; i < 64; i++) {
    float x = vals[t + 256 * i];
    if (x > cm) { cm = x; ci = t + 256 * i; }
  }
  candv[t] = cm; candi[t] = ci;
  __syncthreads();

  if (t < 64) {
    const int l = t;
    for (int it = 0; it < KSEL; it++) {
      // argmax over 256 candidates
      float v = -2e30f; int slot = 0;
#pragma unroll
      for (int j = 0; j < 4; j++) {
        float c = candv[l + 64 * j];
        if (c > v) { v = c; slot = l + 64 * j; }
      }
#pragma unroll
      for (int off = 32; off > 0; off >>= 1) {
        float vv = __shfl_xor(v, off);
        int   ss2 = __shfl_xor(slot, off);
        if (vv > v || (vv == v && ss2 < slot)) { v = vv; slot = ss2; }
      }
      const int gidx = candi[slot];
      if (l == 0) { selv[it] = v; vals[gidx] = -1e30f; }
      // recompute candidate for `slot` (its elements are slot + 256*l)
      float x = vals[slot + 256 * l];
      int  xi = slot + 256 * l;
#pragma unroll
      for (int off = 32; off > 0; off >>= 1) {
        float vv = __shfl_xor(x, off);
        int   ii = __shfl_xor(xi, off);
        if (vv > x || (vv == x && ii < xi)) { x = vv; xi = ii; }
      }
      if (l == 0) { candv[slot] = x; candi[slot] = xi; }
    }
  }
  __syncthreads();

  if (t == 0) {
    float mo = -1e30f;
#pragma unroll
    for (int c = 0; c < CCAM; c++) mo = fmaxf(mo, ov[c]);
    float mcat = fmaxf(mo, selv[0]);   // selv[0] = largest selected
    float S2 = 0.f, sumo = 0.f;
#pragma unroll
    for (int c = 0; c < CCAM; c++) { S2 += __expf((ov[c] - mcat) * T_INV); sumo += ov[c]; }
    for (int i = 0; i < KSEL; i++) S2 += __expf((selv[i] - mcat) * T_INV);
    float lse_c = mcat * T_INV + logf(S2);
    lossk_out[b] = lse_c - (sumo * T_INV) * (1.0f / CCAM);
  }
}

// ---------------------------------------------------------------------------
// Kernel 4: deterministic per-camera segment means -> 2 scalars.
// ---------------------------------------------------------------------------
__global__ __launch_bounds__(256) void finalize_kernel(
    const float* __restrict__ ce, const float* __restrict__ lossk,
    const int* __restrict__ cams, float* __restrict__ out) {
  __shared__ float ce_s[BATCH], lk_s[BATCH];
  __shared__ int   cam_s[BATCH];
  __shared__ float si[CCAM], sk[CCAM], cnt[CCAM];
  const int t = threadIdx.x;
  ce_s[t]  = ce[t];
  lk_s[t]  = lossk[t];
  cam_s[t] = cams[t];
  __syncthreads();
  if (t < CCAM) {
    float a = 0.f, b = 0.f; int n = 0;
    for (int i = 0; i < BATCH; i++) {
      if (cam_s[i] == t) { a += ce_s[i]; b += lk_s[i]; n++; }
    }
    si[t] = a; sk[t] = b; cnt[t] = (float)n;
  }
  __syncthreads();
  if (t == 0) {
    float li = 0.f, lk = 0.f;
    for (int c = 0; c < CCAM; c++) {
      if (cnt[c] > 0.f) { li += si[c] / cnt[c]; lk += sk[c] / cnt[c]; }
    }
    out[0] = li;
    out[1] = 0.5f * lk;
  }
}

// ---------------------------------------------------------------------------
extern "C" void kernel_launch(void* const* d_in, const int* in_sizes, int n_in,
                              void* d_out, int out_size, void* d_ws, size_t ws_size,
                              hipStream_t stream) {
  const float* inputs = (const float*)d_in[0];   // [256][2048]
  const int*   labels = (const int*)d_in[1];     // [256]
  const int*   cams   = (const int*)d_in[2];     // [256]
  const float* tempV  = (const float*)d_in[3];   // [16384][2048]
  float* out = (float*)d_out;

  char* ws = (char*)d_ws;
  unsigned short* xb  = (unsigned short*)ws;                       // 1 MB
  float* logits       = (float*)(ws + (1u << 20));                 // 16 MB
  float* ce           = (float*)(ws + (1u << 20) + (16u << 20));   // 1 KB
  float* lossk        = (float*)(ws + (1u << 20) + (16u << 20) + 1024);

  norm_cast_kernel<<<BATCH, 256, 0, stream>>>(inputs, xb);
  gemm_kernel<<<dim3(BATCH / BM, NMEM / BN), 256, 0, stream>>>(xb, tempV, logits);
  row_loss_kernel<<<BATCH, 256, 0, stream>>>(logits, labels, cams, ce, lossk);
  finalize_kernel<<<1, 256, 0, stream>>>(ce, lossk, cams, out);
}

// Round 4
// 270.379 us; speedup vs baseline: 1.2690x; 1.2184x over previous
//
#include <hip/hip_runtime.h>
#include <hip/hip_bf16.h>

// Problem constants
#define BATCH 256
#define DIM   2048
#define NMEM  16384   // C_CAM * P
#define PCLS  2048
#define CCAM  8
#define KSEL  50
#define T_INV 14.285714285714285714f   // 1 / 0.07
#define NBIN  4096

typedef __bf16 bf16x8 __attribute__((ext_vector_type(8)));
typedef float  f32x4  __attribute__((ext_vector_type(4)));

static __device__ __forceinline__ unsigned int f2bf(float f) {
  unsigned int u = __float_as_uint(f);
  return (u + 0x7FFFu + ((u >> 16) & 1u)) >> 16;   // RNE truncate to bf16
}
static __device__ __forceinline__ unsigned int pk2(float lo, float hi) {
  return f2bf(lo) | (f2bf(hi) << 16);
}
// logits are cosine sims in [-1,1]; map to bin 0..4095 (masked -1e30 -> bin 0)
static __device__ __forceinline__ int binof(float v) {
  float bf = fmaf(v, 1950.4762f, 2048.0f);     // 4096 / 2.1 scale
  bf = fminf(fmaxf(bf, 0.0f), 4095.0f);
  return (int)bf;
}

// ---------------------------------------------------------------------------
// Kernel 1: row-normalize inputs, cast to bf16.  grid=256 blocks x 256 thr
// ---------------------------------------------------------------------------
__global__ __launch_bounds__(256) void norm_cast_kernel(
    const float* __restrict__ in, unsigned short* __restrict__ xb) {
  __shared__ float red[256];
  const int b = blockIdx.x, t = threadIdx.x;
  const float4* row = (const float4*)(in + (size_t)b * DIM);
  float4 a0 = row[t];
  float4 a1 = row[t + 256];
  float ss = a0.x*a0.x + a0.y*a0.y + a0.z*a0.z + a0.w*a0.w
           + a1.x*a1.x + a1.y*a1.y + a1.z*a1.z + a1.w*a1.w;
  red[t] = ss; __syncthreads();
  for (int s = 128; s > 0; s >>= 1) { if (t < s) red[t] += red[t + s]; __syncthreads(); }
  const float rn = rsqrtf(red[0]);
  ushort4 o0, o1;
  o0.x = (unsigned short)f2bf(a0.x*rn); o0.y = (unsigned short)f2bf(a0.y*rn);
  o0.z = (unsigned short)f2bf(a0.z*rn); o0.w = (unsigned short)f2bf(a0.w*rn);
  o1.x = (unsigned short)f2bf(a1.x*rn); o1.y = (unsigned short)f2bf(a1.y*rn);
  o1.z = (unsigned short)f2bf(a1.z*rn); o1.w = (unsigned short)f2bf(a1.w*rn);
  *(ushort4*)&xb[(size_t)b * DIM + t * 4]         = o0;
  *(ushort4*)&xb[(size_t)b * DIM + (t + 256) * 4] = o1;
}

// ---------------------------------------------------------------------------
// Kernel 2: logits = x(bf16) @ tempV^T  (tempV fp32, converted in staging)
// BM=128, BN=64, BK=64. 256 threads = 4 waves (2Mx2N), wave tile 64x32.
// grid = dim3(2, 256) = 512 blocks -> 2 barrier domains per CU.
// BK=64 halves the barrier count (32 iters) so the register prefetch has
// ~2x the MFMA/LDS work to hide its load latency behind.
// ---------------------------------------------------------------------------
#define BM 128
#define BN 64
#define BK 64
#define LDT 72   // padded LDS row stride (bf16 elems): 64 + 8

__global__ __launch_bounds__(256, 2) void gemm_kernel(
    const unsigned short* __restrict__ X,   // [256][2048] bf16
    const float* __restrict__ V,            // [16384][2048] fp32
    float* __restrict__ C) {                // [256][16384] fp32
  __shared__ unsigned short As[BM * LDT];   // 18 KB
  __shared__ unsigned short Bs[BN * LDT];   // 9 KB
  const int t  = threadIdx.x;
  const int m0 = blockIdx.x * BM;
  const int n0 = blockIdx.y * BN;
  const int lane = t & 63;
  const int w    = t >> 6;
  const int wm   = (w >> 1) * 64;   // 0,64
  const int wn   = (w & 1) * 32;    // 0,32

  f32x4 acc[4][2];
#pragma unroll
  for (int i = 0; i < 4; i++)
#pragma unroll
    for (int j = 0; j < 2; j++) acc[i][j] = (f32x4){0.f, 0.f, 0.f, 0.f};

  // staging: A -> thread covers 32 bf16 of one row (128 rows x 2 halves)
  //          B -> thread covers 16 fp32 of one row  (64 rows x 4 quarters)
  const int sr = t >> 1;            // 0..127
  const int sh = (t & 1) * 32;
  const int rb = t >> 2;            // 0..63
  const int cb = (t & 3) * 16;
  const unsigned short* Xp = X + (size_t)(m0 + sr) * DIM + sh;
  const float*          Vp = V + (size_t)(n0 + rb) * DIM + cb;

  // prefetch k=0
  uint4  a0 = *(const uint4*)Xp;
  uint4  a1 = *(const uint4*)(Xp + 8);
  uint4  a2 = *(const uint4*)(Xp + 16);
  uint4  a3 = *(const uint4*)(Xp + 24);
  float4 b0 = *(const float4*)Vp;
  float4 b1 = *(const float4*)(Vp + 4);
  float4 b2 = *(const float4*)(Vp + 8);
  float4 b3 = *(const float4*)(Vp + 12);

  const int fr = lane & 15;
  const int fk = (lane >> 4) * 8;

  for (int k0 = 0; k0 < DIM; k0 += BK) {
    __syncthreads();   // previous iteration's frag reads done
    *(uint4*)&As[sr * LDT + sh]      = a0;
    *(uint4*)&As[sr * LDT + sh + 8]  = a1;
    *(uint4*)&As[sr * LDT + sh + 16] = a2;
    *(uint4*)&As[sr * LDT + sh + 24] = a3;
    uint4 p0, p1;
    p0.x = pk2(b0.x, b0.y); p0.y = pk2(b0.z, b0.w);
    p0.z = pk2(b1.x, b1.y); p0.w = pk2(b1.z, b1.w);
    p1.x = pk2(b2.x, b2.y); p1.y = pk2(b2.z, b2.w);
    p1.z = pk2(b3.x, b3.y); p1.w = pk2(b3.z, b3.w);
    *(uint4*)&Bs[rb * LDT + cb]     = p0;
    *(uint4*)&Bs[rb * LDT + cb + 8] = p1;
    __syncthreads();

    if (k0 + BK < DIM) {  // issue next-tile global loads; consumed next iter
      a0 = *(const uint4*)(Xp + k0 + BK);
      a1 = *(const uint4*)(Xp + k0 + BK + 8);
      a2 = *(const uint4*)(Xp + k0 + BK + 16);
      a3 = *(const uint4*)(Xp + k0 + BK + 24);
      b0 = *(const float4*)(Vp + k0 + BK);
      b1 = *(const float4*)(Vp + k0 + BK + 4);
      b2 = *(const float4*)(Vp + k0 + BK + 8);
      b3 = *(const float4*)(Vp + k0 + BK + 12);
    }

#pragma unroll
    for (int kk = 0; kk < BK; kk += 32) {
      bf16x8 aF[4], bF[2];
#pragma unroll
      for (int i = 0; i < 4; i++)
        aF[i] = *(const bf16x8*)&As[(wm + i * 16 + fr) * LDT + kk + fk];
#pragma unroll
      for (int j = 0; j < 2; j++)
        bF[j] = *(const bf16x8*)&Bs[(wn + j * 16 + fr) * LDT + kk + fk];
#pragma unroll
      for (int i = 0; i < 4; i++)
#pragma unroll
        for (int j = 0; j < 2; j++)
          acc[i][j] = __builtin_amdgcn_mfma_f32_16x16x32_bf16(aF[i], bF[j], acc[i][j], 0, 0, 0);
    }
  }

  // epilogue: C/D layout col=lane&15, row=(lane>>4)*4+reg  [m89/m91 verified]
  const int cr = (lane >> 4) * 4;
  const int cc = lane & 15;
#pragma unroll
  for (int i = 0; i < 4; i++)
#pragma unroll
    for (int j = 0; j < 2; j++)
#pragma unroll
      for (int r = 0; r < 4; r++)
        C[(size_t)(m0 + wm + i * 16 + cr + r) * NMEM + (n0 + wn + j * 16 + cc)] =
            acc[i][j][r];
}

// ---------------------------------------------------------------------------
// Kernel 3: per-row losses. One block (256 thr) per sample.
//  - intra CE over own camera bank (no max-sub: exp(v*14.3) <= 1.6e6, fp32 ok)
//  - mask 8 positives
//  - EXACT top-50 via 4096-bin LDS histogram + suffix scan; bins above the
//    boundary bin sum directly, boundary bin resolved exactly (few elems)
//  - inter logsumexp over {8 ori, 50 sel}
// ---------------------------------------------------------------------------
__global__ __launch_bounds__(256) void row_loss_kernel(
    const float* __restrict__ logits,
    const int* __restrict__ labels, const int* __restrict__ cams,
    float* __restrict__ ce_out, float* __restrict__ lossk_out) {
  __shared__ float vals[NMEM];      // 64 KB
  __shared__ int   hist[NBIN];      // 16 KB
  __shared__ float red[256];
  __shared__ int   pint[256];
  __shared__ float bl[512];         // boundary-bin value list
  __shared__ int   bcount;
  __shared__ int   bstar_s, cabove_s;

  const int b = blockIdx.x, t = threadIdx.x;
  const float4* src = (const float4*)(logits + (size_t)b * NMEM);
#pragma unroll
  for (int i = 0; i < 16; i++) ((float4*)vals)[t + 256 * i] = src[t + 256 * i];
#pragma unroll
  for (int i = 0; i < NBIN / 256; i++) hist[t + 256 * i] = 0;
  if (t == 0) bcount = 0;
  const int cam = cams[b], label = labels[b];
  __syncthreads();

  // ---- intra CE over [cam*PCLS, +PCLS) ----
  const int s0 = cam * PCLS;
  float S = 0.f;
#pragma unroll
  for (int i = 0; i < 8; i++) S += __expf(vals[s0 + t + 256 * i] * T_INV);
  red[t] = S; __syncthreads();
  for (int s = 128; s > 0; s >>= 1) { if (t < s) red[t] += red[t + s]; __syncthreads(); }
  float ov[CCAM]; float sumo = 0.f;
  if (t == 0) {
    ce_out[b] = logf(red[0]) - vals[s0 + label] * T_INV;
#pragma unroll
    for (int c = 0; c < CCAM; c++) { ov[c] = vals[c * PCLS + label]; sumo += ov[c]; }
  }
  __syncthreads();                 // t0's ov reads done before masking
  if (t < CCAM) vals[t * PCLS + label] = -1e30f;
  __syncthreads();

  // ---- histogram ----
#pragma unroll
  for (int i = 0; i < 64; i++) {
    int bin = binof(vals[t + 256 * i]);
    atomicAdd(&hist[bin], 1);
  }
  __syncthreads();

  // ---- suffix scan: find boundary bin b* with S(b*) >= K > S(b*+1) ----
  int ps = 0;
#pragma unroll
  for (int i = 0; i < 16; i++) ps += hist[t * 16 + i];
  pint[t] = ps; __syncthreads();
  if (t == 0) {
    int cum = 0, bstar = 0, cab = 0;
    for (int tc = 255; tc >= 0; tc--) {
      if (cum + pint[tc] >= KSEL) {
        for (int bi = tc * 16 + 15; bi >= tc * 16; bi--) {
          int h = hist[bi];
          if (cum + h >= KSEL) { bstar = bi; cab = cum; break; }
          cum += h;
        }
        break;
      }
      cum += pint[tc];
    }
    bstar_s = bstar; cabove_s = cab;
  }
  __syncthreads();
  const int bstar = bstar_s;

  // ---- selection pass: sum exp over bins > b*, collect boundary bin ----
  float S2 = 0.f;
#pragma unroll
  for (int i = 0; i < 64; i++) {
    float v = vals[t + 256 * i];
    int bin = binof(v);
    if (bin > bstar) S2 += __expf(v * T_INV);
    else if (bin == bstar) {
      int p = atomicAdd(&bcount, 1);
      if (p < 512) bl[p] = v;
    }
  }
  red[t] = S2; __syncthreads();
  for (int s = 128; s > 0; s >>= 1) { if (t < s) red[t] += red[t + s]; __syncthreads(); }

  if (t == 0) {
    float S2tot = red[0];
    int need = KSEL - cabove_s;
    int bc = min(bcount, 512);
    for (int r = 0; r < need; r++) {         // exact top-(need) of boundary bin
      float mx = -1e30f; int mi = 0;
      for (int i = 0; i < bc; i++) if (bl[i] > mx) { mx = bl[i]; mi = i; }
      S2tot += __expf(mx * T_INV);
      bl[mi] = -1e30f;
    }
#pragma unroll
    for (int c = 0; c < CCAM; c++) S2tot += __expf(ov[c] * T_INV);
    lossk_out[b] = logf(S2tot) - (sumo * T_INV) * (1.0f / CCAM);
  }
}

// ---------------------------------------------------------------------------
// Kernel 4: deterministic per-camera segment means -> 2 scalars.
// ---------------------------------------------------------------------------
__global__ __launch_bounds__(256) void finalize_kernel(
    const float* __restrict__ ce, const float* __restrict__ lossk,
    const int* __restrict__ cams, float* __restrict__ out) {
  __shared__ float ce_s[BATCH], lk_s[BATCH];
  __shared__ int   cam_s[BATCH];
  __shared__ float si[CCAM], sk[CCAM], cnt[CCAM];
  const int t = threadIdx.x;
  ce_s[t]  = ce[t];
  lk_s[t]  = lossk[t];
  cam_s[t] = cams[t];
  __syncthreads();
  if (t < CCAM) {
    float a = 0.f, b = 0.f; int n = 0;
    for (int i = 0; i < BATCH; i++) {
      if (cam_s[i] == t) { a += ce_s[i]; b += lk_s[i]; n++; }
    }
    si[t] = a; sk[t] = b; cnt[t] = (float)n;
  }
  __syncthreads();
  if (t == 0) {
    float li = 0.f, lk = 0.f;
    for (int c = 0; c < CCAM; c++) {
      if (cnt[c] > 0.f) { li += si[c] / cnt[c]; lk += sk[c] / cnt[c]; }
    }
    out[0] = li;
    out[1] = 0.5f * lk;
  }
}

// ---------------------------------------------------------------------------
extern "C" void kernel_launch(void* const* d_in, const int* in_sizes, int n_in,
                              void* d_out, int out_size, void* d_ws, size_t ws_size,
                              hipStream_t stream) {
  const float* inputs = (const float*)d_in[0];   // [256][2048]
  const int*   labels = (const int*)d_in[1];     // [256]
  const int*   cams   = (const int*)d_in[2];     // [256]
  const float* tempV  = (const float*)d_in[3];   // [16384][2048]
  float* out = (float*)d_out;

  char* ws = (char*)d_ws;
  unsigned short* xb  = (unsigned short*)ws;                       // 1 MB
  float* logits       = (float*)(ws + (1u << 20));                 // 16 MB
  float* ce           = (float*)(ws + (1u << 20) + (16u << 20));   // 1 KB
  float* lossk        = (float*)(ws + (1u << 20) + (16u << 20) + 1024);

  norm_cast_kernel<<<BATCH, 256, 0, stream>>>(inputs, xb);
  gemm_kernel<<<dim3(BATCH / BM, NMEM / BN), 256, 0, stream>>>(xb, tempV, logits);
  row_loss_kernel<<<BATCH, 256, 0, stream>>>(logits, labels, cams, ce, lossk);
  finalize_kernel<<<1, 256, 0, stream>>>(ce, lossk, cams, out);
}